// Round 2
// baseline (510.956 us; speedup 1.0000x reference)
//
#include <hip/hip_runtime.h>
#include <math.h>

// Mask R-CNN cascade head.
// R2: prep v2 — 2 tiles/block (2x memory ILP), vectorized LDS writes.
//     FC2 + heads: non-split 64x64 GEMM with fused epilogue (bias+relu->bf16
//     for FC2, raw fp32 for heads). Removes reduce dispatches; decode reads a
//     single head buffer. 22 -> 19 dispatches.

#define NROI 256
#define NCLS 80
#define APITCH 40  // 32 k + 8 pad (bf16 elems); 80B row pitch keeps 16B alignment

typedef __attribute__((ext_vector_type(8))) short short8;
typedef __attribute__((ext_vector_type(4))) float f32x4;

__device__ __forceinline__ unsigned short f2bf(float f) {
  unsigned u = __builtin_bit_cast(unsigned, f);
  unsigned r = (u + 0x7FFFu + ((u >> 16) & 1u)) >> 16;  // RNE
  return (unsigned short)r;
}
__device__ __forceinline__ float bf2f(unsigned short u) {
  return __builtin_bit_cast(float, (unsigned)u << 16);
}

struct __attribute__((aligned(8))) US4 { unsigned short a, b, c, d; };

// ---------------- prep: ALL transposes, 2 adjacent 32x32 tiles per block -----
// Each block handles (k0, n0) and (k0, n0+32): per thread 2 independent 16B
// loads, 2 vector LDS writes, 2 independent 8B stores.
// Block ranges (32000 total):
//   [0,8192)       P0 (256,65536) -> Pb0   k-tiles 8 x n-pairs 1024
//   [8192,10240)   P1 (256,16384) -> Pb1   8 x 256
//   [10240,10752)  P2 (256,4096)  -> Pb2   8 x 64
//   [10752,10880)  P3 (256,1024)  -> Pb3   8 x 16
//   [10880,29696)  W1 x3 (12544,1024) -> Wt1[s] (1024,12544) k-permuted, 6272/stage
//   [29696,31232)  W2 x3 (1024,1024)  -> Wt2[s], 512/stage
//   [31232,32000)  [Wc|Wl|pad] x3     -> Wth[s] (512,1024), 256/stage
__global__ __launch_bounds__(256) void prep_kernel(
    const float* __restrict__ P0, const float* __restrict__ P1,
    const float* __restrict__ P2, const float* __restrict__ P3,
    unsigned short* __restrict__ Pb0, unsigned short* __restrict__ Pb1,
    unsigned short* __restrict__ Pb2, unsigned short* __restrict__ Pb3,
    const float* __restrict__ W1a, const float* __restrict__ W1b,
    const float* __restrict__ W1c,
    const float* __restrict__ W2a, const float* __restrict__ W2b,
    const float* __restrict__ W2c,
    const float* __restrict__ Wca, const float* __restrict__ Wcb,
    const float* __restrict__ Wcc,
    const float* __restrict__ Wla, const float* __restrict__ Wlb,
    const float* __restrict__ Wlc,
    unsigned short* __restrict__ Wt1, unsigned short* __restrict__ Wt2,
    unsigned short* __restrict__ Wth) {
  __shared__ unsigned short tile[2][32][36];
  int bid = blockIdx.x;
  int t = threadIdx.x;
  int r = t >> 3;
  int c4 = (t & 7) * 4;

  float4 v0, v1;
  unsigned short *dp0, *dp1;

  if (bid < 10880) {
    // feature transpose: (256, N) -> (N, 256)
    const float* S;
    unsigned short* D;
    int N, idx;
    if (bid < 8192)       { S = P0; D = Pb0; N = 65536; idx = bid; }
    else if (bid < 10240) { S = P1; D = Pb1; N = 16384; idx = bid - 8192; }
    else if (bid < 10752) { S = P2; D = Pb2; N = 4096;  idx = bid - 10240; }
    else                  { S = P3; D = Pb3; N = 1024;  idx = bid - 10752; }
    int k0 = (idx & 7) * 32;
    int n0 = (idx >> 3) * 64;
    const float* src = S + (size_t)(k0 + r) * N + n0 + c4;
    v0 = *(const float4*)src;
    v1 = *(const float4*)(src + 32);
    dp0 = D + (size_t)(n0 + r) * 256 + k0 + c4;
    dp1 = D + (size_t)(n0 + 32 + r) * 256 + k0 + c4;
  } else if (bid < 29696) {
    // W1 transpose with K-permutation: Wt1[s][n][p*256+c] = W1[c*49+p][n]
    int idx = bid - 10880;
    int s = idx / 6272;
    idx -= s * 6272;
    const float* W = (s == 0) ? W1a : (s == 1) ? W1b : W1c;
    int bx = idx % 392;  // kd-tile
    int ny = idx / 392;  // n-pair
    int kd0 = bx * 32;
    int n0 = ny * 64;
    int p = kd0 >> 8;
    int c0 = kd0 & 255;
    const float* src = W + (size_t)((c0 + r) * 49 + p) * 1024 + n0 + c4;
    v0 = *(const float4*)src;
    v1 = *(const float4*)(src + 32);
    unsigned short* D = Wt1 + (size_t)s * 12544 * 1024;
    dp0 = D + (size_t)(n0 + r) * 12544 + kd0 + c4;
    dp1 = D + (size_t)(n0 + 32 + r) * 12544 + kd0 + c4;
  } else if (bid < 31232) {
    // W2 transpose: (1024,1024)
    int idx = bid - 29696;
    int s = idx >> 9;
    idx &= 511;
    const float* W = (s == 0) ? W2a : (s == 1) ? W2b : W2c;
    int k0 = (idx & 31) * 32;
    int n0 = (idx >> 5) * 64;
    const float* src = W + (size_t)(k0 + r) * 1024 + n0 + c4;
    v0 = *(const float4*)src;
    v1 = *(const float4*)(src + 32);
    unsigned short* D = Wt2 + (size_t)s * 1024 * 1024;
    dp0 = D + (size_t)(n0 + r) * 1024 + k0 + c4;
    dp1 = D + (size_t)(n0 + 32 + r) * 1024 + k0 + c4;
  } else {
    // fused head weights: [Wc | Wl | pad] (1024,512) -> (512,1024)
    int idx = bid - 31232;
    int s = idx >> 8;
    idx &= 255;
    const float* wc = (s == 0) ? Wca : (s == 1) ? Wcb : Wcc;
    const float* wl = (s == 0) ? Wla : (s == 1) ? Wlb : Wlc;
    int k0 = (idx & 31) * 32;
    int n0 = (idx >> 5) * 64;
    float a[2][4];
#pragma unroll
    for (int q = 0; q < 2; q++)
#pragma unroll
      for (int j = 0; j < 4; j++) {
        int nn = n0 + q * 32 + c4 + j;
        float x = 0.0f;
        if (nn < 81) x = wc[(size_t)(k0 + r) * 81 + nn];
        else if (nn < 405) x = wl[(size_t)(k0 + r) * 324 + (nn - 81)];
        a[q][j] = x;
      }
    v0.x = a[0][0]; v0.y = a[0][1]; v0.z = a[0][2]; v0.w = a[0][3];
    v1.x = a[1][0]; v1.y = a[1][1]; v1.z = a[1][2]; v1.w = a[1][3];
    unsigned short* D = Wth + (size_t)s * 512 * 1024;
    dp0 = D + (size_t)(n0 + r) * 1024 + k0 + c4;
    dp1 = D + (size_t)(n0 + 32 + r) * 1024 + k0 + c4;
  }

  US4 w0, w1;
  w0.a = f2bf(v0.x); w0.b = f2bf(v0.y); w0.c = f2bf(v0.z); w0.d = f2bf(v0.w);
  w1.a = f2bf(v1.x); w1.b = f2bf(v1.y); w1.c = f2bf(v1.z); w1.d = f2bf(v1.w);
  *(US4*)&tile[0][r][c4] = w0;
  *(US4*)&tile[1][r][c4] = w1;
  __syncthreads();
  US4 o0, o1;
  o0.a = tile[0][c4 + 0][r];
  o0.b = tile[0][c4 + 1][r];
  o0.c = tile[0][c4 + 2][r];
  o0.d = tile[0][c4 + 3][r];
  o1.a = tile[1][c4 + 0][r];
  o1.b = tile[1][c4 + 1][r];
  o1.c = tile[1][c4 + 2][r];
  o1.d = tile[1][c4 + 3][r];
  *(US4*)dp0 = o0;
  *(US4*)dp1 = o1;
}

// ---------------- ROI align pool v2: [H][W][C] bf16 features ----------------
__global__ __launch_bounds__(256) void pool_kernel2(
    const unsigned short* __restrict__ Pb0, const unsigned short* __restrict__ Pb1,
    const unsigned short* __restrict__ Pb2, const unsigned short* __restrict__ Pb3,
    const float* __restrict__ roi, unsigned short* __restrict__ pooled) {
  int t = threadIdx.x;
  int n = blockIdx.y;
  int p = blockIdx.x * 4 + (t >> 6);
  if (p >= 49) return;
  int lane = t & 63;
  int c4 = lane * 4;
  int py = p / 7, px = p % 7;

  float r0 = roi[n * 4 + 0];
  float r1 = roi[n * 4 + 1];
  float r2 = roi[n * 4 + 2];
  float r3 = roi[n * 4 + 3];

  float area = (r2 - r0 + 1.0f) * (r3 - r1 + 1.0f);
  float lf = floorf(4.0f + log2f(sqrtf(area) / 224.0f));
  lf = fminf(fmaxf(lf, 2.0f), 5.0f);
  int lvl = (int)lf - 2;

  float scale;
  int H;
  const unsigned short* fb;
  if (lvl == 0)      { scale = 0.25f;    H = 256; fb = Pb0; }
  else if (lvl == 1) { scale = 0.125f;   H = 128; fb = Pb1; }
  else if (lvl == 2) { scale = 0.0625f;  H = 64;  fb = Pb2; }
  else               { scale = 0.03125f; H = 32;  fb = Pb3; }
  int W = H;

  float y1 = r0 * scale;
  float x1 = r1 * scale;
  float rh = fmaxf(r2 * scale - y1, 1.0f);
  float rw = fmaxf(r3 * scale - x1, 1.0f);
  float bh = rh * (1.0f / 7.0f);
  float bw = rw * (1.0f / 7.0f);

  float a0 = 0.f, a1 = 0.f, a2 = 0.f, a3 = 0.f;
#pragma unroll
  for (int ry = 0; ry < 2; ry++) {
    float yy = y1 + ((float)py + ((float)ry + 0.5f) * 0.5f) * bh;
    bool vy = (yy > -1.0f) && (yy < (float)H);
    float ycl = fminf(fmaxf(yy, 0.0f), (float)(H - 1));
    float y0f = floorf(ycl);
    float ly = ycl - y0f;
    int y0i = (int)y0f;
    int y1i = min(y0i + 1, H - 1);
#pragma unroll
    for (int rx = 0; rx < 2; rx++) {
      float xx = x1 + ((float)px + ((float)rx + 0.5f) * 0.5f) * bw;
      bool vx = (xx > -1.0f) && (xx < (float)W);
      float xcl = fminf(fmaxf(xx, 0.0f), (float)(W - 1));
      float x0f = floorf(xcl);
      float lx = xcl - x0f;
      int x0i = (int)x0f;
      int x1i = min(x0i + 1, W - 1);
      float w00 = (1.f - ly) * (1.f - lx);
      float w01 = (1.f - ly) * lx;
      float w10 = ly * (1.f - lx);
      float w11 = ly * lx;
      if (!(vy && vx)) { w00 = w01 = w10 = w11 = 0.f; }
      ushort4 f00 = *(const ushort4*)(fb + ((size_t)(y0i * W + x0i) * 256 + c4));
      ushort4 f01 = *(const ushort4*)(fb + ((size_t)(y0i * W + x1i) * 256 + c4));
      ushort4 f10 = *(const ushort4*)(fb + ((size_t)(y1i * W + x0i) * 256 + c4));
      ushort4 f11 = *(const ushort4*)(fb + ((size_t)(y1i * W + x1i) * 256 + c4));
      a0 += bf2f(f00.x) * w00 + bf2f(f01.x) * w01 + bf2f(f10.x) * w10 + bf2f(f11.x) * w11;
      a1 += bf2f(f00.y) * w00 + bf2f(f01.y) * w01 + bf2f(f10.y) * w10 + bf2f(f11.y) * w11;
      a2 += bf2f(f00.z) * w00 + bf2f(f01.z) * w01 + bf2f(f10.z) * w10 + bf2f(f11.z) * w11;
      a3 += bf2f(f00.w) * w00 + bf2f(f01.w) * w01 + bf2f(f10.w) * w10 + bf2f(f11.w) * w11;
    }
  }
  ushort4 o;
  o.x = f2bf(a0 * 0.25f);
  o.y = f2bf(a1 * 0.25f);
  o.z = f2bf(a2 * 0.25f);
  o.w = f2bf(a3 * 0.25f);
  *(ushort4*)(pooled + (size_t)n * 12544 + p * 256 + c4) = o;
}

// ---------------- bf16 MFMA GEMM: C = A(MxK) @ Bt(NxK)^T, split-K partials ---------
// (FC1 only: K=12544 needs split-K for occupancy.)
__global__ __launch_bounds__(256) void gemm_bf16(
    const unsigned short* __restrict__ A, const unsigned short* __restrict__ B,
    float* __restrict__ Cpart, int M, int N, int K, int iters) {
  __shared__ unsigned short As[128 * APITCH];
  __shared__ unsigned short Bs[128 * APITCH];
  const int t = threadIdx.x;
  const int n0 = blockIdx.x * 128;
  const int m0 = blockIdx.y * 128;
  const size_t kt0 = (size_t)blockIdx.z * iters * 32;

  const int row = t >> 2;
  const int off = (t & 3) * 8;
  const unsigned short* pa0 = A + (size_t)(m0 + row) * K + kt0 + off;
  const unsigned short* pa1 = pa0 + (size_t)64 * K;
  const unsigned short* pb0 = B + (size_t)(n0 + row) * K + kt0 + off;
  const unsigned short* pb1 = pb0 + (size_t)64 * K;

  const int lane = t & 63;
  const int wave = t >> 6;
  const int wm = (wave >> 1) * 64;
  const int wn = (wave & 1) * 64;
  const int fr = lane & 15;
  const int kq = (lane >> 4) * 8;

  f32x4 acc[4][4];
#pragma unroll
  for (int i = 0; i < 4; i++)
#pragma unroll
    for (int j = 0; j < 4; j++) acc[i][j] = (f32x4){0.f, 0.f, 0.f, 0.f};

  uint4 ra0 = *(const uint4*)pa0;
  uint4 ra1 = *(const uint4*)pa1;
  uint4 rb0 = *(const uint4*)pb0;
  uint4 rb1 = *(const uint4*)pb1;

  for (int it = 0; it < iters; ++it) {
    *(uint4*)&As[row * APITCH + off] = ra0;
    *(uint4*)&As[(row + 64) * APITCH + off] = ra1;
    *(uint4*)&Bs[row * APITCH + off] = rb0;
    *(uint4*)&Bs[(row + 64) * APITCH + off] = rb1;
    __syncthreads();
    if (it + 1 < iters) {
      int d = (it + 1) * 32;
      ra0 = *(const uint4*)(pa0 + d);
      ra1 = *(const uint4*)(pa1 + d);
      rb0 = *(const uint4*)(pb0 + d);
      rb1 = *(const uint4*)(pb1 + d);
    }
    short8 af[4], bfv[4];
#pragma unroll
    for (int f = 0; f < 4; f++)
      af[f] = *(const short8*)&As[(wm + f * 16 + fr) * APITCH + kq];
#pragma unroll
    for (int f = 0; f < 4; f++)
      bfv[f] = *(const short8*)&Bs[(wn + f * 16 + fr) * APITCH + kq];
#pragma unroll
    for (int fm = 0; fm < 4; fm++)
#pragma unroll
      for (int fn = 0; fn < 4; fn++)
        acc[fm][fn] = __builtin_amdgcn_mfma_f32_16x16x32_bf16(af[fm], bfv[fn],
                                                              acc[fm][fn], 0, 0, 0);
    __syncthreads();
  }

  float* Cp = Cpart + (size_t)blockIdx.z * M * N;
  const int colb = n0 + wn + fr;
  const int rowb = m0 + wm + (lane >> 4) * 4;
#pragma unroll
  for (int fm = 0; fm < 4; fm++)
#pragma unroll
    for (int fn = 0; fn < 4; fn++)
#pragma unroll
      for (int r = 0; r < 4; r++)
        Cp[(size_t)(rowb + fm * 16 + r) * N + (colb + fn * 16)] = acc[fm][fn][r];
}

// ---------------- non-split 64x64 GEMM with fused epilogue -------------------
// mode 0: out = bf16( relu(acc + bias[col]) )  (FC2)
// mode 1: out = fp32 acc (raw, bias added in decode)  (heads)
__global__ __launch_bounds__(256) void gemm_fused(
    const unsigned short* __restrict__ A, const unsigned short* __restrict__ B,
    const float* __restrict__ bias, float* __restrict__ outf,
    unsigned short* __restrict__ outb, int N, int K, int mode) {
  __shared__ unsigned short As[64 * APITCH];
  __shared__ unsigned short Bs[64 * APITCH];
  const int t = threadIdx.x;
  const int n0 = blockIdx.x * 64;
  const int m0 = blockIdx.y * 64;

  const int row = t >> 2;
  const int off = (t & 3) * 8;
  const unsigned short* pa = A + (size_t)(m0 + row) * K + off;
  const unsigned short* pb = B + (size_t)(n0 + row) * K + off;

  const int lane = t & 63;
  const int wave = t >> 6;
  const int wm = (wave >> 1) * 32;
  const int wn = (wave & 1) * 32;
  const int fr = lane & 15;
  const int kq = (lane >> 4) * 8;

  f32x4 acc[2][2];
#pragma unroll
  for (int i = 0; i < 2; i++)
#pragma unroll
    for (int j = 0; j < 2; j++) acc[i][j] = (f32x4){0.f, 0.f, 0.f, 0.f};

  uint4 ra = *(const uint4*)pa;
  uint4 rb = *(const uint4*)pb;
  const int iters = K / 32;

  for (int it = 0; it < iters; ++it) {
    *(uint4*)&As[row * APITCH + off] = ra;
    *(uint4*)&Bs[row * APITCH + off] = rb;
    __syncthreads();
    if (it + 1 < iters) {
      int d = (it + 1) * 32;
      ra = *(const uint4*)(pa + d);
      rb = *(const uint4*)(pb + d);
    }
    short8 af[2], bfv[2];
#pragma unroll
    for (int f = 0; f < 2; f++)
      af[f] = *(const short8*)&As[(wm + f * 16 + fr) * APITCH + kq];
#pragma unroll
    for (int f = 0; f < 2; f++)
      bfv[f] = *(const short8*)&Bs[(wn + f * 16 + fr) * APITCH + kq];
#pragma unroll
    for (int fm = 0; fm < 2; fm++)
#pragma unroll
      for (int fn = 0; fn < 2; fn++)
        acc[fm][fn] = __builtin_amdgcn_mfma_f32_16x16x32_bf16(af[fm], bfv[fn],
                                                              acc[fm][fn], 0, 0, 0);
    __syncthreads();
  }

  const int colb = n0 + wn + fr;
  const int rowb = m0 + wm + (lane >> 4) * 4;
#pragma unroll
  for (int fm = 0; fm < 2; fm++)
#pragma unroll
    for (int fn = 0; fn < 2; fn++) {
      int col = colb + fn * 16;
#pragma unroll
      for (int r = 0; r < 4; r++) {
        int rw = rowb + fm * 16 + r;
        float s = acc[fm][fn][r];
        if (mode == 0) {
          s = fmaxf(s + bias[col], 0.0f);
          outb[(size_t)rw * N + col] = f2bf(s);
        } else {
          outf[(size_t)rw * N + col] = s;
        }
      }
    }
}

// ---------------- split-K reduce + bias + relu -> bf16 (FC1 only) -----------
__global__ __launch_bounds__(256) void reduce_bias_relu(
    const float* __restrict__ parts, int nparts, const float* __restrict__ bias,
    unsigned short* __restrict__ outb) {
  int i = blockIdx.x * 256 + threadIdx.x;  // total 256*1024
  float s = 0.0f;
  for (int p = 0; p < nparts; ++p) s += parts[(size_t)p * 262144 + i];
  s = fmaxf(s + bias[i & 1023], 0.0f);
  outb[i] = f2bf(s);
}

// ---------------- decode: softmax, bbox decode, accumulate, argmax -> new roi ----
// headp: single (256 x 512) fp32 buffer (raw head GEMM output, bias added here).
// stage 0 writes pre_b/pre_s/valid; stage 1 accumulates; stage 2 writes final out.
__global__ __launch_bounds__(128) void decode_kernel(
    const float* __restrict__ headp, const float* __restrict__ bc,
    const float* __restrict__ bl,
    const float* __restrict__ roi_in, float* __restrict__ roi_out,
    float* __restrict__ valid,
    float* __restrict__ pre_b, float* __restrict__ pre_s,
    float* __restrict__ out,
    float st0, float st1, float st2, float st3, int stage) {
  int n = blockIdx.x;
  int t = threadIdx.x;
  __shared__ float red[128];
  __shared__ int redi[128];
  __shared__ float sroi[4];
  __shared__ float boxes[NCLS][4];

  if (t < 4) sroi[t] = roi_in[n * 4 + t];
  float l = -INFINITY;
  if (t < 81) l = headp[n * 512 + t] + bc[t];
  red[t] = l;
  __syncthreads();
#pragma unroll
  for (int s = 64; s > 0; s >>= 1) {
    if (t < s) red[t] = fmaxf(red[t], red[t + s]);
    __syncthreads();
  }
  float mx = red[0];
  __syncthreads();
  red[t] = (t < 81) ? expf(l - mx) : 0.0f;
  __syncthreads();
#pragma unroll
  for (int s = 64; s > 0; s >>= 1) {
    if (t < s) red[t] += red[t + s];
    __syncthreads();
  }
  float denom = red[0];
  __syncthreads();

  float score = -INFINITY;
  if (t < NCLS) {
    float lj = headp[n * 512 + (t + 1)] + bc[t + 1];
    score = expf(lj - mx) / denom;
    float lp[4];
#pragma unroll
    for (int j = 0; j < 4; j++)
      lp[j] = headp[n * 512 + 81 + (t + 1) * 4 + j] + bl[(t + 1) * 4 + j];
    float dy = lp[0] * st0;
    float dx = lp[1] * st1;
    float dh = lp[2] * st2;
    float dw = lp[3] * st3;
    float h_ = sroi[2] - sroi[0];
    float w_ = sroi[3] - sroi[1];
    float cy = sroi[0] + h_ * 0.5f;
    float cx = sroi[1] + w_ * 0.5f;
    float ny = dy * h_ + cy;
    float nx = dx * w_ + cx;
    float nh = expf(dh) * h_;
    float nw = expf(dw) * w_;
    float b0 = ny - nh * 0.5f;
    float b1v = nx - nw * 0.5f;
    float b2v = ny + nh * 0.5f;
    float b3v = nx + nw * 0.5f;
    int o = (n * NCLS + t) * 4;
    if (stage == 0) {
      pre_b[o + 0] = b0;
      pre_b[o + 1] = b1v;
      pre_b[o + 2] = b2v;
      pre_b[o + 3] = b3v;
      pre_s[n * NCLS + t] = score;
    } else if (stage == 1) {
      pre_b[o + 0] += b0;
      pre_b[o + 1] += b1v;
      pre_b[o + 2] += b2v;
      pre_b[o + 3] += b3v;
      pre_s[n * NCLS + t] += score;
    } else {
      float vm = valid[n] * (1.0f / 3.0f);
      out[o + 0] = (pre_b[o + 0] + b0) * vm;
      out[o + 1] = (pre_b[o + 1] + b1v) * vm;
      out[o + 2] = (pre_b[o + 2] + b2v) * vm;
      out[o + 3] = (pre_b[o + 3] + b3v) * vm;
      out[NROI * NCLS * 4 + n * NCLS + t] = (pre_s[n * NCLS + t] + score) * vm;
    }
    if (stage < 2) {
      boxes[t][0] = b0;
      boxes[t][1] = b1v;
      boxes[t][2] = b2v;
      boxes[t][3] = b3v;
    }
  }
  if (stage < 2) {
    red[t] = score;
    redi[t] = t;
    __syncthreads();
    for (int s = 64; s > 0; s >>= 1) {
      if (t < s) {
        float o2 = red[t + s];
        int oi = redi[t + s];
        if (o2 > red[t] || (o2 == red[t] && oi < redi[t])) {
          red[t] = o2;
          redi[t] = oi;
        }
      }
      __syncthreads();
    }
    if (t == 0) {
      int best = redi[0];
      float ry1 = fminf(fmaxf(boxes[best][0], 0.0f), 1024.0f);
      float rx1 = fminf(fmaxf(boxes[best][1], 0.0f), 1024.0f);
      float ry2 = fminf(fmaxf(boxes[best][2], 0.0f), 1024.0f);
      float rx2 = fminf(fmaxf(boxes[best][3], 0.0f), 1024.0f);
      roi_out[n * 4 + 0] = ry1;
      roi_out[n * 4 + 1] = rx1;
      roi_out[n * 4 + 2] = ry2;
      roi_out[n * 4 + 3] = rx2;
      float hh = ry2 - ry1, ww = rx2 - rx1;
      bool ok = (hh >= 16.0f && ww >= 16.0f);
      if (stage == 0) valid[n] = ok ? 1.0f : 0.0f;
      else if (!ok) valid[n] = 0.0f;
    }
  }
}

extern "C" void kernel_launch(void* const* d_in, const int* in_sizes, int n_in,
                              void* d_out, int out_size, void* d_ws, size_t ws_size,
                              hipStream_t stream) {
  const float* P0 = (const float*)d_in[0];
  const float* P1 = (const float*)d_in[1];
  const float* P2 = (const float*)d_in[2];
  const float* P3 = (const float*)d_in[3];
  const float* rois = (const float*)d_in[4];
  float* out = (float*)d_out;
  float* ws = (float*)d_ws;

  // ---- ws layout (fp32 region first, then bf16 region) ----
  float* roi   = ws;                               // 1024
  float* valid = roi + 1024;                       // 256
  float* pre_b = valid + 256;                      // 81920
  float* pre_s = pre_b + 81920;                    // 20480
  float* part1 = pre_s + 20480;                    // 14 * 262144
  float* parth = part1 + (size_t)14 * 262144;      // 131072
  unsigned short* pooledb = (unsigned short*)(parth + 131072);  // 256*12544
  unsigned short* Wt1 = pooledb + (size_t)256 * 12544;   // 3 * 1024*12544
  unsigned short* Wt2 = Wt1 + (size_t)3 * 12544 * 1024;  // 3 * 1024*1024
  unsigned short* Wth = Wt2 + (size_t)3 * 1024 * 1024;   // 3 * 512*1024
  unsigned short* h1b = Wth + (size_t)3 * 512 * 1024;    // 256*1024
  unsigned short* h2b = h1b + (size_t)256 * 1024;        // 256*1024
  unsigned short* Pb0 = h2b + (size_t)256 * 1024;        // 65536*256
  unsigned short* Pb1 = Pb0 + (size_t)65536 * 256;       // 16384*256
  unsigned short* Pb2 = Pb1 + (size_t)16384 * 256;       // 4096*256
  unsigned short* Pb3 = Pb2 + (size_t)4096 * 256;        // 1024*256

  // One prep kernel for every transpose: features + 3 stages of weights.
  prep_kernel<<<32000, 256, 0, stream>>>(
      P0, P1, P2, P3, Pb0, Pb1, Pb2, Pb3,
      (const float*)d_in[5 + 0 * 8 + 0], (const float*)d_in[5 + 1 * 8 + 0],
      (const float*)d_in[5 + 2 * 8 + 0],
      (const float*)d_in[5 + 0 * 8 + 2], (const float*)d_in[5 + 1 * 8 + 2],
      (const float*)d_in[5 + 2 * 8 + 2],
      (const float*)d_in[5 + 0 * 8 + 4], (const float*)d_in[5 + 1 * 8 + 4],
      (const float*)d_in[5 + 2 * 8 + 4],
      (const float*)d_in[5 + 0 * 8 + 6], (const float*)d_in[5 + 1 * 8 + 6],
      (const float*)d_in[5 + 2 * 8 + 6],
      Wt1, Wt2, Wth);

  const float stds[3][4] = {
      {0.1f, 0.1f, 0.2f, 0.2f},
      {0.05f, 0.05f, 0.1f, 0.1f},
      {1.0f / 30.0f, 1.0f / 30.0f, 1.0f / 15.0f, 1.0f / 15.0f}};

  for (int s = 0; s < 3; s++) {
    const float* b1 = (const float*)d_in[5 + s * 8 + 1];
    const float* b2 = (const float*)d_in[5 + s * 8 + 3];
    const float* bc = (const float*)d_in[5 + s * 8 + 5];
    const float* bl = (const float*)d_in[5 + s * 8 + 7];
    const float* roi_src = (s == 0) ? rois : roi;

    pool_kernel2<<<dim3(13, 256), 256, 0, stream>>>(Pb0, Pb1, Pb2, Pb3, roi_src,
                                                    pooledb);

    // FC1: (256x12544)@(12544x1024)^T -> part1[14], iters = 392/14 = 28
    gemm_bf16<<<dim3(8, 2, 14), 256, 0, stream>>>(
        pooledb, Wt1 + (size_t)s * 12544 * 1024, part1, 256, 1024, 12544, 28);
    reduce_bias_relu<<<1024, 256, 0, stream>>>(part1, 14, b1, h1b);

    // FC2: (256x1024)@(1024x1024)^T + bias + relu -> h2b, fused epilogue
    gemm_fused<<<dim3(16, 4), 256, 0, stream>>>(
        h1b, Wt2 + (size_t)s * 1024 * 1024, b2, nullptr, h2b, 1024, 1024, 0);

    // fused heads: (256x1024)@(1024x512)^T -> parth (raw fp32)
    gemm_fused<<<dim3(8, 4), 256, 0, stream>>>(
        h2b, Wth + (size_t)s * 512 * 1024, nullptr, parth, nullptr, 512, 1024, 1);

    decode_kernel<<<256, 128, 0, stream>>>(parth, bc, bl, roi_src, roi, valid,
                                           pre_b, pre_s, out, stds[s][0],
                                           stds[s][1], stds[s][2], stds[s][3], s);
  }
}

// Round 3
// 478.107 us; speedup vs baseline: 1.0687x; 1.0687x over previous
//
#include <hip/hip_runtime.h>
#include <math.h>

// Mask R-CNN cascade head.
// R3: revert FC2/heads to R1 split-K GEMM (R2's 64x64 fused GEMM regressed).
//     prep v3: balanced 64(k) x 32(n) tiles -> BOTH read and write sides use
//     128B aligned segments (writes were 64B partial-line before). LDS pitch 66
//     (33 dwords, ==1 mod 32) -> conflict-free transpose writes.

#define NROI 256
#define NCLS 80
#define APITCH 40  // 32 k + 8 pad (bf16 elems); 80B row pitch keeps 16B alignment

typedef __attribute__((ext_vector_type(8))) short short8;
typedef __attribute__((ext_vector_type(4))) float f32x4;

__device__ __forceinline__ unsigned short f2bf(float f) {
  unsigned u = __builtin_bit_cast(unsigned, f);
  unsigned r = (u + 0x7FFFu + ((u >> 16) & 1u)) >> 16;  // RNE
  return (unsigned short)r;
}
__device__ __forceinline__ float bf2f(unsigned short u) {
  return __builtin_bit_cast(float, (unsigned)u << 16);
}

// ---------------- prep: ALL transposes, 64(k) x 32(n) tiles ------------------
// Per thread: 2x float4 loads (128B segments per src row), 8 bf16 LDS writes
// (2-way max, free), 1x 16B store (8 lanes = one aligned 128B line per dst row).
// Block ranges (32000 total, same boundaries as R2):
//   [0,10880)      features P0..P3 (256,N) -> Pb (N,256); 4 k-tiles x N/32
//   [10880,29696)  W1 x3 (12544,1024) -> Wt1[s] (1024,12544) k-permuted
//   [29696,31232)  W2 x3 (1024,1024)  -> Wt2[s]
//   [31232,32000)  [Wc|Wl|pad] x3     -> Wth[s] (512,1024)
__global__ __launch_bounds__(256) void prep_kernel(
    const float* __restrict__ P0, const float* __restrict__ P1,
    const float* __restrict__ P2, const float* __restrict__ P3,
    unsigned short* __restrict__ Pb0, unsigned short* __restrict__ Pb1,
    unsigned short* __restrict__ Pb2, unsigned short* __restrict__ Pb3,
    const float* __restrict__ W1a, const float* __restrict__ W1b,
    const float* __restrict__ W1c,
    const float* __restrict__ W2a, const float* __restrict__ W2b,
    const float* __restrict__ W2c,
    const float* __restrict__ Wca, const float* __restrict__ Wcb,
    const float* __restrict__ Wcc,
    const float* __restrict__ Wla, const float* __restrict__ Wlb,
    const float* __restrict__ Wlc,
    unsigned short* __restrict__ Wt1, unsigned short* __restrict__ Wt2,
    unsigned short* __restrict__ Wth) {
  __shared__ unsigned short lt[32][66];  // [n][k], pitch 66 ushorts (33 dwords)
  int bid = blockIdx.x;
  int t = threadIdx.x;
  int r0 = t >> 3;       // src k-row, iter 0 (0..31); iter 1 adds 32
  int c = t & 7;         // float4 column within 32-float src row

  float4 v0, v1;
  unsigned short* D;     // dst base
  size_t drow;           // dst row index base = n0
  int Kd;                // dst row stride (bf16 elems)
  int k0;                // dst k offset of tile

  if (bid < 10880) {
    // features: (256, N) -> (N, 256)
    const float* S;
    int N, idx;
    if (bid < 8192)       { S = P0; D = Pb0; N = 65536; idx = bid; }
    else if (bid < 10240) { S = P1; D = Pb1; N = 16384; idx = bid - 8192; }
    else if (bid < 10752) { S = P2; D = Pb2; N = 4096;  idx = bid - 10240; }
    else                  { S = P3; D = Pb3; N = 1024;  idx = bid - 10752; }
    k0 = (idx & 3) * 64;
    int n0 = (idx >> 2) * 32;
    Kd = 256;
    drow = n0;
    const float* a = S + (size_t)(k0 + r0) * N + n0 + c * 4;
    v0 = *(const float4*)a;
    v1 = *(const float4*)(a + (size_t)32 * N);
  } else if (bid < 29696) {
    // W1 k-permuted: Wt1[s][n][p*256+cc] = W1[cc*49+p][n]
    int idx = bid - 10880;
    int s = idx / 6272;
    idx -= s * 6272;
    const float* W = (s == 0) ? W1a : (s == 1) ? W1b : W1c;
    int kd0 = (idx % 196) * 64;
    int n0 = (idx / 196) * 32;
    int p = kd0 >> 8;
    int c0 = kd0 & 255;
    k0 = kd0;
    Kd = 12544;
    drow = n0;
    D = Wt1 + (size_t)s * 12544 * 1024;
    const float* a = W + (size_t)((c0 + r0) * 49 + p) * 1024 + n0 + c * 4;
    v0 = *(const float4*)a;
    v1 = *(const float4*)(a + (size_t)32 * 49 * 1024);
  } else if (bid < 31232) {
    // W2: (1024,1024) -> (1024,1024)
    int idx = bid - 29696;
    int s = idx >> 9;
    idx &= 511;
    const float* W = (s == 0) ? W2a : (s == 1) ? W2b : W2c;
    k0 = (idx & 15) * 64;
    int n0 = (idx >> 4) * 32;
    Kd = 1024;
    drow = n0;
    D = Wt2 + (size_t)s * 1024 * 1024;
    const float* a = W + (size_t)(k0 + r0) * 1024 + n0 + c * 4;
    v0 = *(const float4*)a;
    v1 = *(const float4*)(a + (size_t)32 * 1024);
  } else {
    // fused head weights: [Wc | Wl | pad] (1024,512) -> (512,1024)
    int idx = bid - 31232;
    int s = idx >> 8;
    idx &= 255;
    const float* wc = (s == 0) ? Wca : (s == 1) ? Wcb : Wcc;
    const float* wl = (s == 0) ? Wla : (s == 1) ? Wlb : Wlc;
    k0 = (idx & 15) * 64;
    int n0 = (idx >> 4) * 32;
    Kd = 1024;
    drow = n0;
    D = Wth + (size_t)s * 512 * 1024;
    float a0[4], a1[4];
#pragma unroll
    for (int j = 0; j < 4; j++) {
      int nn = n0 + c * 4 + j;
      float x0 = 0.0f, x1 = 0.0f;
      if (nn < 81) {
        x0 = wc[(size_t)(k0 + r0) * 81 + nn];
        x1 = wc[(size_t)(k0 + r0 + 32) * 81 + nn];
      } else if (nn < 405) {
        x0 = wl[(size_t)(k0 + r0) * 324 + (nn - 81)];
        x1 = wl[(size_t)(k0 + r0 + 32) * 324 + (nn - 81)];
      }
      a0[j] = x0;
      a1[j] = x1;
    }
    v0.x = a0[0]; v0.y = a0[1]; v0.z = a0[2]; v0.w = a0[3];
    v1.x = a1[0]; v1.y = a1[1]; v1.z = a1[2]; v1.w = a1[3];
  }

  // LDS transpose write: lt[n_local][k_local]
  const float* pv0 = (const float*)&v0;
  const float* pv1 = (const float*)&v1;
#pragma unroll
  for (int j = 0; j < 4; j++) {
    lt[c * 4 + j][r0] = f2bf(pv0[j]);
    lt[c * 4 + j][r0 + 32] = f2bf(pv1[j]);
  }
  __syncthreads();

  // store: thread t -> dst row (drow + t>>3), 16B at k0 + (t&7)*8
  int n = t >> 3;
  int k8 = (t & 7) * 8;
  const unsigned int* lrow = (const unsigned int*)&lt[n][k8];  // 4B aligned
  uint4 o;
  o.x = lrow[0];
  o.y = lrow[1];
  o.z = lrow[2];
  o.w = lrow[3];
  *(uint4*)(D + (drow + n) * (size_t)Kd + k0 + k8) = o;
}

// ---------------- ROI align pool v2: [H][W][C] bf16 features ----------------
__global__ __launch_bounds__(256) void pool_kernel2(
    const unsigned short* __restrict__ Pb0, const unsigned short* __restrict__ Pb1,
    const unsigned short* __restrict__ Pb2, const unsigned short* __restrict__ Pb3,
    const float* __restrict__ roi, unsigned short* __restrict__ pooled) {
  int t = threadIdx.x;
  int n = blockIdx.y;
  int p = blockIdx.x * 4 + (t >> 6);
  if (p >= 49) return;
  int lane = t & 63;
  int c4 = lane * 4;
  int py = p / 7, px = p % 7;

  float r0 = roi[n * 4 + 0];
  float r1 = roi[n * 4 + 1];
  float r2 = roi[n * 4 + 2];
  float r3 = roi[n * 4 + 3];

  float area = (r2 - r0 + 1.0f) * (r3 - r1 + 1.0f);
  float lf = floorf(4.0f + log2f(sqrtf(area) / 224.0f));
  lf = fminf(fmaxf(lf, 2.0f), 5.0f);
  int lvl = (int)lf - 2;

  float scale;
  int H;
  const unsigned short* fb;
  if (lvl == 0)      { scale = 0.25f;    H = 256; fb = Pb0; }
  else if (lvl == 1) { scale = 0.125f;   H = 128; fb = Pb1; }
  else if (lvl == 2) { scale = 0.0625f;  H = 64;  fb = Pb2; }
  else               { scale = 0.03125f; H = 32;  fb = Pb3; }
  int W = H;

  float y1 = r0 * scale;
  float x1 = r1 * scale;
  float rh = fmaxf(r2 * scale - y1, 1.0f);
  float rw = fmaxf(r3 * scale - x1, 1.0f);
  float bh = rh * (1.0f / 7.0f);
  float bw = rw * (1.0f / 7.0f);

  float a0 = 0.f, a1 = 0.f, a2 = 0.f, a3 = 0.f;
#pragma unroll
  for (int ry = 0; ry < 2; ry++) {
    float yy = y1 + ((float)py + ((float)ry + 0.5f) * 0.5f) * bh;
    bool vy = (yy > -1.0f) && (yy < (float)H);
    float ycl = fminf(fmaxf(yy, 0.0f), (float)(H - 1));
    float y0f = floorf(ycl);
    float ly = ycl - y0f;
    int y0i = (int)y0f;
    int y1i = min(y0i + 1, H - 1);
#pragma unroll
    for (int rx = 0; rx < 2; rx++) {
      float xx = x1 + ((float)px + ((float)rx + 0.5f) * 0.5f) * bw;
      bool vx = (xx > -1.0f) && (xx < (float)W);
      float xcl = fminf(fmaxf(xx, 0.0f), (float)(W - 1));
      float x0f = floorf(xcl);
      float lx = xcl - x0f;
      int x0i = (int)x0f;
      int x1i = min(x0i + 1, W - 1);
      float w00 = (1.f - ly) * (1.f - lx);
      float w01 = (1.f - ly) * lx;
      float w10 = ly * (1.f - lx);
      float w11 = ly * lx;
      if (!(vy && vx)) { w00 = w01 = w10 = w11 = 0.f; }
      ushort4 f00 = *(const ushort4*)(fb + ((size_t)(y0i * W + x0i) * 256 + c4));
      ushort4 f01 = *(const ushort4*)(fb + ((size_t)(y0i * W + x1i) * 256 + c4));
      ushort4 f10 = *(const ushort4*)(fb + ((size_t)(y1i * W + x0i) * 256 + c4));
      ushort4 f11 = *(const ushort4*)(fb + ((size_t)(y1i * W + x1i) * 256 + c4));
      a0 += bf2f(f00.x) * w00 + bf2f(f01.x) * w01 + bf2f(f10.x) * w10 + bf2f(f11.x) * w11;
      a1 += bf2f(f00.y) * w00 + bf2f(f01.y) * w01 + bf2f(f10.y) * w10 + bf2f(f11.y) * w11;
      a2 += bf2f(f00.z) * w00 + bf2f(f01.z) * w01 + bf2f(f10.z) * w10 + bf2f(f11.z) * w11;
      a3 += bf2f(f00.w) * w00 + bf2f(f01.w) * w01 + bf2f(f10.w) * w10 + bf2f(f11.w) * w11;
    }
  }
  ushort4 o;
  o.x = f2bf(a0 * 0.25f);
  o.y = f2bf(a1 * 0.25f);
  o.z = f2bf(a2 * 0.25f);
  o.w = f2bf(a3 * 0.25f);
  *(ushort4*)(pooled + (size_t)n * 12544 + p * 256 + c4) = o;
}

// ---------------- bf16 MFMA GEMM: C = A(MxK) @ Bt(NxK)^T, split-K partials ---------
__global__ __launch_bounds__(256) void gemm_bf16(
    const unsigned short* __restrict__ A, const unsigned short* __restrict__ B,
    float* __restrict__ Cpart, int M, int N, int K, int iters) {
  __shared__ unsigned short As[128 * APITCH];
  __shared__ unsigned short Bs[128 * APITCH];
  const int t = threadIdx.x;
  const int n0 = blockIdx.x * 128;
  const int m0 = blockIdx.y * 128;
  const size_t kt0 = (size_t)blockIdx.z * iters * 32;

  const int row = t >> 2;
  const int off = (t & 3) * 8;
  const unsigned short* pa0 = A + (size_t)(m0 + row) * K + kt0 + off;
  const unsigned short* pa1 = pa0 + (size_t)64 * K;
  const unsigned short* pb0 = B + (size_t)(n0 + row) * K + kt0 + off;
  const unsigned short* pb1 = pb0 + (size_t)64 * K;

  const int lane = t & 63;
  const int wave = t >> 6;
  const int wm = (wave >> 1) * 64;
  const int wn = (wave & 1) * 64;
  const int fr = lane & 15;
  const int kq = (lane >> 4) * 8;

  f32x4 acc[4][4];
#pragma unroll
  for (int i = 0; i < 4; i++)
#pragma unroll
    for (int j = 0; j < 4; j++) acc[i][j] = (f32x4){0.f, 0.f, 0.f, 0.f};

  uint4 ra0 = *(const uint4*)pa0;
  uint4 ra1 = *(const uint4*)pa1;
  uint4 rb0 = *(const uint4*)pb0;
  uint4 rb1 = *(const uint4*)pb1;

  for (int it = 0; it < iters; ++it) {
    *(uint4*)&As[row * APITCH + off] = ra0;
    *(uint4*)&As[(row + 64) * APITCH + off] = ra1;
    *(uint4*)&Bs[row * APITCH + off] = rb0;
    *(uint4*)&Bs[(row + 64) * APITCH + off] = rb1;
    __syncthreads();
    if (it + 1 < iters) {
      int d = (it + 1) * 32;
      ra0 = *(const uint4*)(pa0 + d);
      ra1 = *(const uint4*)(pa1 + d);
      rb0 = *(const uint4*)(pb0 + d);
      rb1 = *(const uint4*)(pb1 + d);
    }
    short8 af[4], bfv[4];
#pragma unroll
    for (int f = 0; f < 4; f++)
      af[f] = *(const short8*)&As[(wm + f * 16 + fr) * APITCH + kq];
#pragma unroll
    for (int f = 0; f < 4; f++)
      bfv[f] = *(const short8*)&Bs[(wn + f * 16 + fr) * APITCH + kq];
#pragma unroll
    for (int fm = 0; fm < 4; fm++)
#pragma unroll
      for (int fn = 0; fn < 4; fn++)
        acc[fm][fn] = __builtin_amdgcn_mfma_f32_16x16x32_bf16(af[fm], bfv[fn],
                                                              acc[fm][fn], 0, 0, 0);
    __syncthreads();
  }

  float* Cp = Cpart + (size_t)blockIdx.z * M * N;
  const int colb = n0 + wn + fr;
  const int rowb = m0 + wm + (lane >> 4) * 4;
#pragma unroll
  for (int fm = 0; fm < 4; fm++)
#pragma unroll
    for (int fn = 0; fn < 4; fn++)
#pragma unroll
      for (int r = 0; r < 4; r++)
        Cp[(size_t)(rowb + fm * 16 + r) * N + (colb + fn * 16)] = acc[fm][fn][r];
}

// ---------------- split-K reduce + bias + relu -> bf16 ----------------
__global__ __launch_bounds__(256) void reduce_bias_relu(
    const float* __restrict__ parts, int nparts, const float* __restrict__ bias,
    unsigned short* __restrict__ outb) {
  int i = blockIdx.x * 256 + threadIdx.x;  // total 256*1024
  float s = 0.0f;
  for (int p = 0; p < nparts; ++p) s += parts[(size_t)p * 262144 + i];
  s = fmaxf(s + bias[i & 1023], 0.0f);
  outb[i] = f2bf(s);
}

// ---------------- decode: softmax, bbox decode, accumulate, argmax -> new roi ----
// headp: 4 split-K partials of (256 x 512); summed inline.
// stage 0 writes pre_b/pre_s/valid; stage 1 accumulates; stage 2 writes final out.
__global__ __launch_bounds__(128) void decode_kernel(
    const float* __restrict__ headp, const float* __restrict__ bc,
    const float* __restrict__ bl,
    const float* __restrict__ roi_in, float* __restrict__ roi_out,
    float* __restrict__ valid,
    float* __restrict__ pre_b, float* __restrict__ pre_s,
    float* __restrict__ out,
    float st0, float st1, float st2, float st3, int stage) {
  int n = blockIdx.x;
  int t = threadIdx.x;
  __shared__ float red[128];
  __shared__ int redi[128];
  __shared__ float sroi[4];
  __shared__ float boxes[NCLS][4];

  if (t < 4) sroi[t] = roi_in[n * 4 + t];
  float l = -INFINITY;
  if (t < 81) {
    float s = 0.f;
#pragma unroll
    for (int z = 0; z < 4; z++) s += headp[(size_t)z * 131072 + n * 512 + t];
    l = s + bc[t];
  }
  red[t] = l;
  __syncthreads();
#pragma unroll
  for (int s = 64; s > 0; s >>= 1) {
    if (t < s) red[t] = fmaxf(red[t], red[t + s]);
    __syncthreads();
  }
  float mx = red[0];
  __syncthreads();
  red[t] = (t < 81) ? expf(l - mx) : 0.0f;
  __syncthreads();
#pragma unroll
  for (int s = 64; s > 0; s >>= 1) {
    if (t < s) red[t] += red[t + s];
    __syncthreads();
  }
  float denom = red[0];
  __syncthreads();

  float score = -INFINITY;
  if (t < NCLS) {
    float lj = 0.f;
#pragma unroll
    for (int z = 0; z < 4; z++) lj += headp[(size_t)z * 131072 + n * 512 + (t + 1)];
    lj += bc[t + 1];
    score = expf(lj - mx) / denom;
    float lp[4];
#pragma unroll
    for (int j = 0; j < 4; j++) {
      float s = 0.f;
#pragma unroll
      for (int z = 0; z < 4; z++)
        s += headp[(size_t)z * 131072 + n * 512 + 81 + (t + 1) * 4 + j];
      lp[j] = s + bl[(t + 1) * 4 + j];
    }
    float dy = lp[0] * st0;
    float dx = lp[1] * st1;
    float dh = lp[2] * st2;
    float dw = lp[3] * st3;
    float h_ = sroi[2] - sroi[0];
    float w_ = sroi[3] - sroi[1];
    float cy = sroi[0] + h_ * 0.5f;
    float cx = sroi[1] + w_ * 0.5f;
    float ny = dy * h_ + cy;
    float nx = dx * w_ + cx;
    float nh = expf(dh) * h_;
    float nw = expf(dw) * w_;
    float b0 = ny - nh * 0.5f;
    float b1v = nx - nw * 0.5f;
    float b2v = ny + nh * 0.5f;
    float b3v = nx + nw * 0.5f;
    int o = (n * NCLS + t) * 4;
    if (stage == 0) {
      pre_b[o + 0] = b0;
      pre_b[o + 1] = b1v;
      pre_b[o + 2] = b2v;
      pre_b[o + 3] = b3v;
      pre_s[n * NCLS + t] = score;
    } else if (stage == 1) {
      pre_b[o + 0] += b0;
      pre_b[o + 1] += b1v;
      pre_b[o + 2] += b2v;
      pre_b[o + 3] += b3v;
      pre_s[n * NCLS + t] += score;
    } else {
      float vm = valid[n] * (1.0f / 3.0f);
      out[o + 0] = (pre_b[o + 0] + b0) * vm;
      out[o + 1] = (pre_b[o + 1] + b1v) * vm;
      out[o + 2] = (pre_b[o + 2] + b2v) * vm;
      out[o + 3] = (pre_b[o + 3] + b3v) * vm;
      out[NROI * NCLS * 4 + n * NCLS + t] = (pre_s[n * NCLS + t] + score) * vm;
    }
    if (stage < 2) {
      boxes[t][0] = b0;
      boxes[t][1] = b1v;
      boxes[t][2] = b2v;
      boxes[t][3] = b3v;
    }
  }
  if (stage < 2) {
    red[t] = score;
    redi[t] = t;
    __syncthreads();
    for (int s = 64; s > 0; s >>= 1) {
      if (t < s) {
        float o2 = red[t + s];
        int oi = redi[t + s];
        if (o2 > red[t] || (o2 == red[t] && oi < redi[t])) {
          red[t] = o2;
          redi[t] = oi;
        }
      }
      __syncthreads();
    }
    if (t == 0) {
      int best = redi[0];
      float ry1 = fminf(fmaxf(boxes[best][0], 0.0f), 1024.0f);
      float rx1 = fminf(fmaxf(boxes[best][1], 0.0f), 1024.0f);
      float ry2 = fminf(fmaxf(boxes[best][2], 0.0f), 1024.0f);
      float rx2 = fminf(fmaxf(boxes[best][3], 0.0f), 1024.0f);
      roi_out[n * 4 + 0] = ry1;
      roi_out[n * 4 + 1] = rx1;
      roi_out[n * 4 + 2] = ry2;
      roi_out[n * 4 + 3] = rx2;
      float hh = ry2 - ry1, ww = rx2 - rx1;
      bool ok = (hh >= 16.0f && ww >= 16.0f);
      if (stage == 0) valid[n] = ok ? 1.0f : 0.0f;
      else if (!ok) valid[n] = 0.0f;
    }
  }
}

extern "C" void kernel_launch(void* const* d_in, const int* in_sizes, int n_in,
                              void* d_out, int out_size, void* d_ws, size_t ws_size,
                              hipStream_t stream) {
  const float* P0 = (const float*)d_in[0];
  const float* P1 = (const float*)d_in[1];
  const float* P2 = (const float*)d_in[2];
  const float* P3 = (const float*)d_in[3];
  const float* rois = (const float*)d_in[4];
  float* out = (float*)d_out;
  float* ws = (float*)d_ws;

  // ---- ws layout (fp32 region first, then bf16 region) ----
  float* roi   = ws;                               // 1024
  float* valid = roi + 1024;                       // 256
  float* pre_b = valid + 256;                      // 81920
  float* pre_s = pre_b + 81920;                    // 20480
  float* part1 = pre_s + 20480;                    // 14 * 262144
  float* part2 = part1 + (size_t)14 * 262144;      // 8 * 262144
  float* parth = part2 + (size_t)8 * 262144;       // 4 * 131072
  unsigned short* pooledb = (unsigned short*)(parth + (size_t)4 * 131072);  // 256*12544
  unsigned short* Wt1 = pooledb + (size_t)256 * 12544;   // 3 * 1024*12544
  unsigned short* Wt2 = Wt1 + (size_t)3 * 12544 * 1024;  // 3 * 1024*1024
  unsigned short* Wth = Wt2 + (size_t)3 * 1024 * 1024;   // 3 * 512*1024
  unsigned short* h1b = Wth + (size_t)3 * 512 * 1024;    // 256*1024
  unsigned short* h2b = h1b + (size_t)256 * 1024;        // 256*1024
  unsigned short* Pb0 = h2b + (size_t)256 * 1024;        // 65536*256
  unsigned short* Pb1 = Pb0 + (size_t)65536 * 256;       // 16384*256
  unsigned short* Pb2 = Pb1 + (size_t)16384 * 256;       // 4096*256
  unsigned short* Pb3 = Pb2 + (size_t)4096 * 256;        // 1024*256

  // One prep kernel for every transpose: features + 3 stages of weights.
  prep_kernel<<<32000, 256, 0, stream>>>(
      P0, P1, P2, P3, Pb0, Pb1, Pb2, Pb3,
      (const float*)d_in[5 + 0 * 8 + 0], (const float*)d_in[5 + 1 * 8 + 0],
      (const float*)d_in[5 + 2 * 8 + 0],
      (const float*)d_in[5 + 0 * 8 + 2], (const float*)d_in[5 + 1 * 8 + 2],
      (const float*)d_in[5 + 2 * 8 + 2],
      (const float*)d_in[5 + 0 * 8 + 4], (const float*)d_in[5 + 1 * 8 + 4],
      (const float*)d_in[5 + 2 * 8 + 4],
      (const float*)d_in[5 + 0 * 8 + 6], (const float*)d_in[5 + 1 * 8 + 6],
      (const float*)d_in[5 + 2 * 8 + 6],
      Wt1, Wt2, Wth);

  const float stds[3][4] = {
      {0.1f, 0.1f, 0.2f, 0.2f},
      {0.05f, 0.05f, 0.1f, 0.1f},
      {1.0f / 30.0f, 1.0f / 30.0f, 1.0f / 15.0f, 1.0f / 15.0f}};

  for (int s = 0; s < 3; s++) {
    const float* b1 = (const float*)d_in[5 + s * 8 + 1];
    const float* b2 = (const float*)d_in[5 + s * 8 + 3];
    const float* bc = (const float*)d_in[5 + s * 8 + 5];
    const float* bl = (const float*)d_in[5 + s * 8 + 7];
    const float* roi_src = (s == 0) ? rois : roi;

    pool_kernel2<<<dim3(13, 256), 256, 0, stream>>>(Pb0, Pb1, Pb2, Pb3, roi_src,
                                                    pooledb);

    // FC1: (256x12544)@(12544x1024)^T -> part1[14], iters = 392/14 = 28
    gemm_bf16<<<dim3(8, 2, 14), 256, 0, stream>>>(
        pooledb, Wt1 + (size_t)s * 12544 * 1024, part1, 256, 1024, 12544, 28);
    reduce_bias_relu<<<1024, 256, 0, stream>>>(part1, 14, b1, h1b);

    // FC2: (256x1024)@(1024x1024)^T -> part2[8], iters = 4
    gemm_bf16<<<dim3(8, 2, 8), 256, 0, stream>>>(
        h1b, Wt2 + (size_t)s * 1024 * 1024, part2, 256, 1024, 1024, 4);
    reduce_bias_relu<<<1024, 256, 0, stream>>>(part2, 8, b2, h2b);

    // fused heads: (256x1024)@(1024x512)^T -> parth[4], iters = 8
    gemm_bf16<<<dim3(4, 2, 4), 256, 0, stream>>>(
        h2b, Wth + (size_t)s * 512 * 1024, parth, 256, 512, 1024, 8);

    decode_kernel<<<256, 128, 0, stream>>>(parth, bc, bl, roi_src, roi, valid,
                                           pre_b, pre_s, out, stds[s][0],
                                           stds[s][1], stds[s][2], stds[s][3], s);
  }
}